// Round 8
// baseline (385.393 us; speedup 1.0000x reference)
//
#include <hip/hip_runtime.h>
#include <hip/hip_bf16.h>

typedef __hip_bfloat16 bf16;
typedef __attribute__((ext_vector_type(8))) short short8;   // 8 bf16 (4 VGPRs)
typedef __attribute__((ext_vector_type(4))) float f32x4;

constexpr int D     = 1024;
constexpr int T     = 2048;
constexpr int BATCH = 2;
constexpr int ROWS  = BATCH * T;   // 4096
constexpr int NH    = 16;
constexpr int DKEY  = 64;
constexpr int QKVN  = 3 * D;       // 3072
constexpr int FFNN  = 4 * D;       // 4096

static __device__ __forceinline__ float b2f(bf16 x) { return __bfloat162float(x); }
static __device__ __forceinline__ bf16  f2b(float x) { return __float2bfloat16(x); }
static __device__ __forceinline__ float loadf(const bf16* p)  { return __bfloat162float(*p); }
static __device__ __forceinline__ float loadf(const float* p) { return *p; }
static __device__ __forceinline__ float fast_exp2(float x) { return __builtin_amdgcn_exp2f(x); }
static __device__ __forceinline__ unsigned short f2bu(float x) {
    return __bfloat16_as_ushort(__float2bfloat16(x));
}
static __device__ __forceinline__ float us2f(unsigned short u) {
    union { unsigned int i; float f; } c; c.i = ((unsigned int)u) << 16; return c.f;
}

// ---------- fp32 [R][C] -> bf16 [C][R] transpose + downcast ----------
__global__ __launch_bounds__(256) void transpose_cast(const float* __restrict__ in,
                                                      bf16* __restrict__ out,
                                                      int R, int C)
{
    __shared__ float tile[32][33];
    int c0 = blockIdx.x * 32, r0 = blockIdx.y * 32;
    int tx = threadIdx.x & 31, ty = threadIdx.x >> 5;  // 8 rows per pass
#pragma unroll
    for (int i = 0; i < 32; i += 8)
        tile[ty + i][tx] = in[(size_t)(r0 + ty + i) * C + c0 + tx];
    __syncthreads();
#pragma unroll
    for (int i = 0; i < 32; i += 8)
        out[(size_t)(c0 + ty + i) * R + r0 + tx] = f2b(tile[tx][ty + i]);
}

// ---------- LayerNorm: one block per row of 1024, fp32 gamma/beta, bf16 out ----------
template <typename TIN>
__global__ __launch_bounds__(256) void ln_kernel(const TIN* __restrict__ X,
                                                 const float* __restrict__ g,
                                                 const float* __restrict__ b,
                                                 bf16* __restrict__ out)
{
    int row = blockIdx.x;
    int tid = threadIdx.x;
    const TIN* xr = X + (size_t)row * D;
    float v[4];
#pragma unroll
    for (int i = 0; i < 4; ++i) v[i] = loadf(xr + tid + i * 256);

    float s1 = v[0] + v[1] + v[2] + v[3];
    float s2 = v[0]*v[0] + v[1]*v[1] + v[2]*v[2] + v[3]*v[3];
#pragma unroll
    for (int off = 32; off; off >>= 1) {
        s1 += __shfl_xor(s1, off);
        s2 += __shfl_xor(s2, off);
    }
    __shared__ float red[8];
    int lane = tid & 63, w = tid >> 6;
    if (lane == 0) { red[w] = s1; red[4 + w] = s2; }
    __syncthreads();
    s1 = red[0] + red[1] + red[2] + red[3];
    s2 = red[4] + red[5] + red[6] + red[7];

    float mu   = s1 * (1.0f / D);
    float var  = s2 * (1.0f / D) - mu * mu;
    float rstd = rsqrtf(var + 1e-5f);

    bf16* orow = out + (size_t)row * D;
#pragma unroll
    for (int i = 0; i < 4; ++i) {
        int c = tid + i * 256;
        orow[c] = f2b((v[i] - mu) * rstd * g[c] + b[c]);
    }
}

// ---------- Pipelined MFMA GEMM (unchanged, passing) ----------
template <int BM, int RELU, int RES, int OUTF32>
__global__ __launch_bounds__(256) void mfma_gemm(
    const bf16* __restrict__ A, const bf16* __restrict__ Bt,
    const float* __restrict__ bias, const void* __restrict__ resid,
    void* __restrict__ out, int M, int N, int K)
{
    constexpr int LDSK = 40;       // 32 + 8 pad (80 B stride)
    constexpr int MT   = BM / 32;  // m-frags per wave (2 or 4)
    __shared__ __align__(16) unsigned short As[2][BM * LDSK];
    __shared__ __align__(16) unsigned short Bs[2][128 * LDSK];

    int tid  = threadIdx.x;
    int m0   = blockIdx.y * BM, n0 = blockIdx.x * 128;
    int lane = tid & 63, wave = tid >> 6;
    int wm = (wave >> 1) * (MT * 16), wn = (wave & 1) * 64;
    int c15 = lane & 15, quad = lane >> 4;

    f32x4 acc[MT][4] = {};

    int brow = tid >> 1, bseg = (tid & 1) * 16;
    int arow, aseg;
    if constexpr (BM == 128) { arow = tid >> 1; aseg = (tid & 1) * 16; }
    else                     { arow = tid >> 2; aseg = (tid & 3) * 8;  }
    const bf16* aptr = A  + (size_t)(m0 + arow) * K + aseg;
    const bf16* bptr = Bt + (size_t)(n0 + brow) * K + bseg;

    int nk = K >> 5;
    uint4 ra0, ra1, rb0, rb1;
    ra0 = *(const uint4*)(aptr);
    if constexpr (BM == 128) ra1 = *(const uint4*)(aptr + 8);
    rb0 = *(const uint4*)(bptr);
    rb1 = *(const uint4*)(bptr + 8);

    for (int kt = 0; kt < nk; ++kt) {
        int buf = kt & 1;
        {
            unsigned short* asl = &As[buf][arow * LDSK + aseg];
            unsigned short* bsl = &Bs[buf][brow * LDSK + bseg];
            *(uint4*)asl = ra0;
            if constexpr (BM == 128) *(uint4*)(asl + 8) = ra1;
            *(uint4*)bsl       = rb0;
            *(uint4*)(bsl + 8) = rb1;
        }
        __syncthreads();
        if (kt + 1 < nk) {
            int ko = (kt + 1) * 32;
            ra0 = *(const uint4*)(aptr + ko);
            if constexpr (BM == 128) ra1 = *(const uint4*)(aptr + ko + 8);
            rb0 = *(const uint4*)(bptr + ko);
            rb1 = *(const uint4*)(bptr + ko + 8);
        }
        short8 af[MT], bfr[4];
#pragma unroll
        for (int t = 0; t < MT; ++t)
            af[t]  = *(const short8*)&As[buf][(wm + t * 16 + c15) * LDSK + quad * 8];
#pragma unroll
        for (int t = 0; t < 4; ++t)
            bfr[t] = *(const short8*)&Bs[buf][(wn + t * 16 + c15) * LDSK + quad * 8];
#pragma unroll
        for (int mt = 0; mt < MT; ++mt)
#pragma unroll
            for (int nt = 0; nt < 4; ++nt)
                acc[mt][nt] = __builtin_amdgcn_mfma_f32_16x16x32_bf16(
                    af[mt], bfr[nt], acc[mt][nt], 0, 0, 0);
    }

#pragma unroll
    for (int mt = 0; mt < MT; ++mt) {
#pragma unroll
        for (int nt = 0; nt < 4; ++nt) {
            f32x4 v4 = acc[mt][nt];
            int gc = n0 + wn + nt * 16 + c15;
            float bb = bias[gc];
#pragma unroll
            for (int r = 0; r < 4; ++r) {
                int gr = m0 + wm + mt * 16 + quad * 4 + r;
                float v = v4[r] + bb;
                if constexpr (RELU) v = fmaxf(v, 0.0f);
                size_t idx = (size_t)gr * N + gc;
                if constexpr (RES == 1) v += b2f(((const bf16*)resid)[idx]);
                if constexpr (RES == 2) v += ((const float*)resid)[idx];
                if constexpr (OUTF32) ((float*)out)[idx] = v;
                else                  ((bf16*)out)[idx] = f2b(v);
            }
        }
    }
}

// ---------- Split-K MFMA GEMM: P += A[:, ks:ks+klen] @ Bt[:, ks:ks+klen]^T ----------
// BM=BN=128, grid (N/128, M/128, KSLICES). fp32 atomic accumulation into
// pre-zeroed P. Raises FFN2 (N=1024) from 256 blocks @BM=64 to 512 @BM=128:
// 21.9 FLOP/LDS-byte tile shape at 2 blocks/CU.
__global__ __launch_bounds__(256) void mfma_gemm_splitk(
    const bf16* __restrict__ A, const bf16* __restrict__ Bt,
    float* __restrict__ P, int M, int N, int K, int klen)
{
    constexpr int LDSK = 40;
    __shared__ __align__(16) unsigned short As[2][128 * LDSK];
    __shared__ __align__(16) unsigned short Bs[2][128 * LDSK];

    int tid  = threadIdx.x;
    int m0   = blockIdx.y * 128, n0 = blockIdx.x * 128;
    int ks   = blockIdx.z * klen;
    int lane = tid & 63, wave = tid >> 6;
    int wm = (wave >> 1) * 64, wn = (wave & 1) * 64;
    int c15 = lane & 15, quad = lane >> 4;

    f32x4 acc[4][4] = {};

    int srow = tid >> 1, sseg = (tid & 1) * 16;
    const bf16* aptr = A  + (size_t)(m0 + srow) * K + ks + sseg;
    const bf16* bptr = Bt + (size_t)(n0 + srow) * K + ks + sseg;

    int nk = klen >> 5;
    uint4 ra0 = *(const uint4*)(aptr), ra1 = *(const uint4*)(aptr + 8);
    uint4 rb0 = *(const uint4*)(bptr), rb1 = *(const uint4*)(bptr + 8);

    for (int kt = 0; kt < nk; ++kt) {
        int buf = kt & 1;
        {
            unsigned short* asl = &As[buf][srow * LDSK + sseg];
            unsigned short* bsl = &Bs[buf][srow * LDSK + sseg];
            *(uint4*)asl       = ra0;
            *(uint4*)(asl + 8) = ra1;
            *(uint4*)bsl       = rb0;
            *(uint4*)(bsl + 8) = rb1;
        }
        __syncthreads();
        if (kt + 1 < nk) {
            int ko = (kt + 1) * 32;
            ra0 = *(const uint4*)(aptr + ko);
            ra1 = *(const uint4*)(aptr + ko + 8);
            rb0 = *(const uint4*)(bptr + ko);
            rb1 = *(const uint4*)(bptr + ko + 8);
        }
        short8 af[4], bfr[4];
#pragma unroll
        for (int t = 0; t < 4; ++t)
            af[t]  = *(const short8*)&As[buf][(wm + t * 16 + c15) * LDSK + quad * 8];
#pragma unroll
        for (int t = 0; t < 4; ++t)
            bfr[t] = *(const short8*)&Bs[buf][(wn + t * 16 + c15) * LDSK + quad * 8];
#pragma unroll
        for (int mt = 0; mt < 4; ++mt)
#pragma unroll
            for (int nt = 0; nt < 4; ++nt)
                acc[mt][nt] = __builtin_amdgcn_mfma_f32_16x16x32_bf16(
                    af[mt], bfr[nt], acc[mt][nt], 0, 0, 0);
    }

#pragma unroll
    for (int mt = 0; mt < 4; ++mt)
#pragma unroll
        for (int nt = 0; nt < 4; ++nt) {
            int gc = n0 + wn + nt * 16 + c15;
#pragma unroll
            for (int r = 0; r < 4; ++r) {
                int gr = m0 + wm + mt * 16 + quad * 4 + r;
                unsafeAtomicAdd(&P[(size_t)gr * N + gc], acc[mt][nt][r]);
            }
        }
}

// ---------- reduce: out = P + bias + X1 (bf16 resid), fp32 out ----------
__global__ __launch_bounds__(256) void reduce_out(const float* __restrict__ P,
                                                  const bf16* __restrict__ X1,
                                                  const float* __restrict__ bias,
                                                  float* __restrict__ out)
{
    int row = blockIdx.x;
    int c   = threadIdx.x * 4;
    size_t idx = (size_t)row * D + c;
    float4 p = *(const float4*)(P + idx);
    float4 bb = *(const float4*)(bias + c);
    ushort4 x = *(const ushort4*)((const unsigned short*)X1 + idx);
    float4 o;
    o.x = p.x + bb.x + us2f(x.x);
    o.y = p.y + bb.y + us2f(x.y);
    o.z = p.z + bb.z + us2f(x.z);
    o.w = p.w + bb.w + us2f(x.w);
    *(float4*)(out + idx) = o;
}

// ---------- MFMA flash attention (unchanged from round 7, passing) ----------
__global__ __launch_bounds__(256) void flash_attn(const bf16* __restrict__ qkv,
                                                  bf16* __restrict__ ctx)
{
    constexpr int KROW = 72;
    constexpr float CSC = 0.18033688011112042f;  // 0.125 * log2(e)
    constexpr float MSH = 12.0f;                 // fixed exp2-domain shift

    __shared__ __align__(16) unsigned short Qs[128 * KROW];
    __shared__ __align__(16) unsigned short Ks[64 * KROW];
    __shared__ __align__(16) unsigned short Vt[64 * KROW];
    unsigned short* Pt = Qs;

    int bx = blockIdx.x;
    int bh = bx & 31;
    int qi = 15 - (bx >> 5);
    int h  = bh & 15, b = bh >> 4;
    int q0 = qi * 128;

    int tid = threadIdx.x, lane = tid & 63, w = tid >> 6;
    int c15 = lane & 15, quad = lane >> 4;

    const bf16* base = qkv + (size_t)b * T * QKVN;

    {
        int row = tid >> 1, half = tid & 1;
        const bf16* src = base + (size_t)(q0 + row) * QKVN + h * 64 + half * 32;
        unsigned short* dst = &Qs[row * KROW + half * 32];
        uint4 v0 = *(const uint4*)(src);
        uint4 v1 = *(const uint4*)(src + 8);
        uint4 v2 = *(const uint4*)(src + 16);
        uint4 v3 = *(const uint4*)(src + 24);
        *(uint4*)(dst)      = v0;
        *(uint4*)(dst + 8)  = v1;
        *(uint4*)(dst + 16) = v2;
        *(uint4*)(dst + 24) = v3;
    }
    __syncthreads();

    short8 qf[2][2];
#pragma unroll
    for (int qt = 0; qt < 2; ++qt)
#pragma unroll
        for (int s = 0; s < 2; ++s)
            qf[qt][s] = *(const short8*)&Qs[(w * 32 + qt * 16 + c15) * KROW + s * 32 + quad * 8];

    short8 ones;
#pragma unroll
    for (int i = 0; i < 8; ++i) ones[i] = (short)0x3F80;  // bf16 1.0

    f32x4 Ot[4][2] = {};
    f32x4 lacc[2]  = {};

    int nkt   = q0 / 64 + 2;
    int wqmin = q0 + w * 32;
    int wqmax = wqmin + 31;

    for (int kt = 0; kt < nkt; ++kt) {
        int k0 = kt * 64;
        int key = tid >> 2, seg = tid & 3;
        const bf16* ksrc = base + (size_t)(k0 + key) * QKVN + D + h * 64 + seg * 16;
        uint4 kv0 = *(const uint4*)ksrc;
        uint4 kv1 = *(const uint4*)(ksrc + 8);
        int keyp = (tid & 31) * 2, dk0 = (tid >> 5) * 8;
        const bf16* vsrc = base + (size_t)(k0 + keyp) * QKVN + 2 * D + h * 64 + dk0;
        uint4 vv0 = *(const uint4*)vsrc;
        uint4 vv1 = *(const uint4*)(vsrc + QKVN);

        __syncthreads();
        {
            unsigned short* kd = &Ks[key * KROW + seg * 16];
            *(uint4*)kd       = kv0;
            *(uint4*)(kd + 8) = kv1;
            const unsigned short* lo = (const unsigned short*)&vv0;
            const unsigned short* hi = (const unsigned short*)&vv1;
#pragma unroll
            for (int j = 0; j < 8; ++j) {
                unsigned int pk = (unsigned int)lo[j] | ((unsigned int)hi[j] << 16);
                *(unsigned int*)&Vt[(dk0 + j) * KROW + keyp] = pk;
            }
        }
        __syncthreads();

        if (k0 <= wqmax) {
            f32x4 St[4][2] = {};
#pragma unroll
            for (int s = 0; s < 2; ++s)
#pragma unroll
                for (int ktm = 0; ktm < 4; ++ktm) {
                    short8 kf = *(const short8*)&Ks[(ktm * 16 + c15) * KROW + s * 32 + quad * 8];
#pragma unroll
                    for (int qt = 0; qt < 2; ++qt)
                        St[ktm][qt] = __builtin_amdgcn_mfma_f32_16x16x32_bf16(
                            kf, qf[qt][s], St[ktm][qt], 0, 0, 0);
                }

            bool diag = (k0 + 63 > wqmin);
#pragma unroll
            for (int ktm = 0; ktm < 4; ++ktm)
#pragma unroll
                for (int qt = 0; qt < 2; ++qt) {
                    ushort4 pk;
                    int q_g = wqmin + qt * 16 + c15;
#pragma unroll
                    for (int r = 0; r < 4; ++r) {
                        float p = fast_exp2(fmaf(St[ktm][qt][r], CSC, -MSH));
                        if (diag && (k0 + ktm * 16 + quad * 4 + r > q_g)) p = 0.0f;
                        ((unsigned short*)&pk)[r] = f2bu(p);
                    }
                    *(ushort4*)&Pt[(w * 32 + qt * 16 + c15) * KROW + ktm * 16 + quad * 4] = pk;
                }

#pragma unroll
            for (int s = 0; s < 2; ++s) {
                short8 pf[2];
#pragma unroll
                for (int qt = 0; qt < 2; ++qt)
                    pf[qt] = *(const short8*)&Pt[(w * 32 + qt * 16 + c15) * KROW + s * 32 + quad * 8];
#pragma unroll
                for (int qt = 0; qt < 2; ++qt)
                    lacc[qt] = __builtin_amdgcn_mfma_f32_16x16x32_bf16(ones, pf[qt], lacc[qt], 0, 0, 0);
#pragma unroll
                for (int dt = 0; dt < 4; ++dt) {
                    short8 vf = *(const short8*)&Vt[(dt * 16 + c15) * KROW + s * 32 + quad * 8];
#pragma unroll
                    for (int qt = 0; qt < 2; ++qt)
                        Ot[dt][qt] = __builtin_amdgcn_mfma_f32_16x16x32_bf16(
                            vf, pf[qt], Ot[dt][qt], 0, 0, 0);
                }
            }
        }
    }

#pragma unroll
    for (int qt = 0; qt < 2; ++qt) {
        float inv = 1.0f / lacc[qt][0];
        int grow = b * T + q0 + w * 32 + qt * 16 + c15;
        bf16* dst = ctx + (size_t)grow * D + h * 64 + quad * 4;
#pragma unroll
        for (int dt = 0; dt < 4; ++dt) {
            ushort4 pk;
#pragma unroll
            for (int r = 0; r < 4; ++r)
                ((unsigned short*)&pk)[r] = f2bu(Ot[dt][qt][r] * inv);
            *(ushort4*)(dst + dt * 16) = pk;
        }
    }
}

extern "C" void kernel_launch(void* const* d_in, const int* in_sizes, int n_in,
                              void* d_out, int out_size, void* d_ws, size_t ws_size,
                              hipStream_t stream)
{
    const float* X    = (const float*)d_in[0];
    const float* Wqkv = (const float*)d_in[1];
    const float* bqkv = (const float*)d_in[2];
    const float* Wo   = (const float*)d_in[3];
    const float* bo   = (const float*)d_in[4];
    const float* W1   = (const float*)d_in[5];
    const float* b1   = (const float*)d_in[6];
    const float* W2   = (const float*)d_in[7];
    const float* b2   = (const float*)d_in[8];
    const float* ln1g = (const float*)d_in[9];
    const float* ln1b = (const float*)d_in[10];
    const float* ln2g = (const float*)d_in[11];
    const float* ln2b = (const float*)d_in[12];
    float* out = (float*)d_out;

    // Workspace layout (peak 72 MiB). Lifetimes:
    //   Wqkv_t [t0..QKV]  Wo_t [t0..Wo]  W1_t [t0..FFN1]  W2_t [t0..FFN2]
    //   Xn [LN1..QKV] / X1 [Wo..reduce_out] (same slot, disjoint)
    //   Xn2 [LN2..FFN1]   qkv [QKV..flash]   ctx [flash..Wo]
    //   mid [FFN1..FFN2] overlays dead qkv+ctx
    //   P0  [memset..reduce_out] overlays dead Wqkv_t/Wo_t/W1_t
    char* ws = (char*)d_ws;
    bf16*  Wqkv_t = (bf16*)(ws + 0);          //  6 MiB [3072][1024]
    bf16*  Wo_t   = (bf16*)(ws + 6291456);    //  2 MiB [1024][1024]
    bf16*  W1_t   = (bf16*)(ws + 8388608);    //  8 MiB [4096][1024]
    bf16*  W2_t   = (bf16*)(ws + 16777216);   //  8 MiB [1024][4096]
    bf16*  Xn     = (bf16*)(ws + 25165824);   //  8 MiB
    bf16*  X1     = Xn;
    bf16*  Xn2    = (bf16*)(ws + 33554432);   //  8 MiB
    bf16*  qkv    = (bf16*)(ws + 41943040);   // 24 MiB (40..64)
    bf16*  ctx    = (bf16*)(ws + 67108864);   //  8 MiB (64..72)
    bf16*  mid    = (bf16*)(ws + 41943040);   // 32 MiB (40..72)
    float* P0     = (float*)(ws + 0);         // 16 MiB (0..16)

    transpose_cast<<<dim3(QKVN / 32, D / 32), 256, 0, stream>>>(Wqkv, Wqkv_t, D, QKVN);
    transpose_cast<<<dim3(D / 32, D / 32), 256, 0, stream>>>(Wo, Wo_t, D, D);
    transpose_cast<<<dim3(FFNN / 32, D / 32), 256, 0, stream>>>(W1, W1_t, D, FFNN);
    transpose_cast<<<dim3(D / 32, FFNN / 32), 256, 0, stream>>>(W2, W2_t, FFNN, D);

    ln_kernel<float><<<ROWS, 256, 0, stream>>>(X, ln1g, ln1b, Xn);
    mfma_gemm<128, 0, 0, 0><<<dim3(QKVN / 128, ROWS / 128), 256, 0, stream>>>(
        Xn, Wqkv_t, bqkv, nullptr, qkv, ROWS, QKVN, D);
    flash_attn<<<512, 256, 0, stream>>>(qkv, ctx);
    mfma_gemm<64, 0, 2, 0><<<dim3(D / 128, ROWS / 64), 256, 0, stream>>>(
        ctx, Wo_t, bo, X, X1, ROWS, D, D);
    ln_kernel<bf16><<<ROWS, 256, 0, stream>>>(X1, ln2g, ln2b, Xn2);
    mfma_gemm<128, 1, 0, 0><<<dim3(FFNN / 128, ROWS / 128), 256, 0, stream>>>(
        Xn2, W1_t, b1, nullptr, mid, ROWS, FFNN, D);
    // FFN2 split-K2: zero P0, accumulate both K-halves, fused bias+residual epilogue
    hipMemsetAsync(P0, 0, (size_t)ROWS * D * sizeof(float), stream);
    mfma_gemm_splitk<<<dim3(D / 128, ROWS / 128, 2), 256, 0, stream>>>(
        mid, W2_t, P0, ROWS, D, FFNN, FFNN / 2);
    reduce_out<<<ROWS, 256, 0, stream>>>(P0, X1, b2, out);
}